// Round 6
// baseline (172.722 us; speedup 1.0000x reference)
//
#include <hip/hip_runtime.h>

#define E_DIM 64
#define N_E   1024
#define N_PTS 32768

// d_out layout (floats):
#define OFF_ZQ   1
#define OFF_PERP 2097153
#define OFF_OH   2097154
#define OFF_IDX  35651586

// d_ws layout (bytes):
#define WS_LOSS    0        // float
#define WS_FIXCNT  4        // uint
#define WS_COUNTS  256      // uint[1024]
#define WS_NORMS   8192     // float[1024]        (ne, from eprep)
#define WS_IDX     16384    // int[32768]         (ends 147456)
#define WS_FIXLIST 147456   // int[8192]          (ends 180224)
#define WS_EBHL    311296   // ushort[1024*128]   hi[64],lo[64] per code
#define FIXCAP     8192

typedef __attribute__((ext_vector_type(8))) short short8;
typedef __attribute__((ext_vector_type(4))) float f32x4;

// numpy pairwise_sum replication for n=64 over squares (fp32, no contraction)
__device__ __forceinline__ float np_sum64_sq(const float* a) {
#pragma clang fp contract(off)
    float r0 = a[0] * a[0];
    float r1 = a[1] * a[1];
    float r2 = a[2] * a[2];
    float r3 = a[3] * a[3];
    float r4 = a[4] * a[4];
    float r5 = a[5] * a[5];
    float r6 = a[6] * a[6];
    float r7 = a[7] * a[7];
#pragma unroll
    for (int m = 1; m < 8; ++m) {
        r0 += a[8 * m + 0] * a[8 * m + 0];
        r1 += a[8 * m + 1] * a[8 * m + 1];
        r2 += a[8 * m + 2] * a[8 * m + 2];
        r3 += a[8 * m + 3] * a[8 * m + 3];
        r4 += a[8 * m + 4] * a[8 * m + 4];
        r5 += a[8 * m + 5] * a[8 * m + 5];
        r6 += a[8 * m + 6] * a[8 * m + 6];
        r7 += a[8 * m + 7] * a[8 * m + 7];
    }
    return ((r0 + r1) + (r2 + r3)) + ((r4 + r5) + (r6 + r7));
}

__device__ __forceinline__ unsigned short rn_bf16(float f) {
    unsigned int u = __float_as_uint(f);
    return (unsigned short)((u + 0x7FFFu + ((u >> 16) & 1u)) >> 16);
}
__device__ __forceinline__ float bf16_to_f(unsigned short h) {
    return __uint_as_float(((unsigned int)h) << 16);
}

// prep: codebook -> hi/lo bf16 + ||e||^2; block 0 also zeroes ws accumulators
__global__ void eprep_kernel(const float* __restrict__ emb,
                             unsigned short* __restrict__ ebhl,
                             float* __restrict__ norms,
                             unsigned int* __restrict__ ws_head,
                             unsigned int* __restrict__ counts) {
    int k = blockIdx.x * blockDim.x + threadIdx.x;
    if (blockIdx.x == 0) {
        if (threadIdx.x < 2) ws_head[threadIdx.x] = 0u;
        *reinterpret_cast<uint4*>(&counts[threadIdx.x * 4]) = make_uint4(0u, 0u, 0u, 0u);
    }
    if (k >= N_E) return;
    float er[E_DIM];
    const float4* e4 = reinterpret_cast<const float4*>(emb) + (size_t)k * (E_DIM / 4);
#pragma unroll
    for (int i = 0; i < E_DIM / 4; ++i)
        *reinterpret_cast<float4*>(&er[i * 4]) = e4[i];
    norms[k] = np_sum64_sq(er);
    unsigned int* rh = (unsigned int*)(ebhl + (size_t)k * 128);
    unsigned int* rl = rh + 32;
#pragma unroll
    for (int c = 0; c < E_DIM; c += 2) {
        unsigned short h0 = rn_bf16(er[c]);
        unsigned short h1 = rn_bf16(er[c + 1]);
        unsigned short l0 = rn_bf16(er[c] - bf16_to_f(h0));
        unsigned short l1 = rn_bf16(er[c + 1] - bf16_to_f(h1));
        rh[c / 2] = (unsigned int)h0 | ((unsigned int)h1 << 16);
        rl[c / 2] = (unsigned int)l0 | ((unsigned int)l1 << 16);
    }
}

// Phase A: MFMA split-bf16 distance + argmin + fused one-hot.
// 2048 blocks x 256 thr (4 waves). Block = 16 points; wave = 16 pts x 256 codes.
#define LOADT(B0, B1, B2, B3, t) {                                   \
        const unsigned short* tp_ = ep + (size_t)(t) * 2048;         \
        B0 = *reinterpret_cast<const short8*>(tp_);                  \
        B1 = *reinterpret_cast<const short8*>(tp_ + 32);             \
        B2 = *reinterpret_cast<const short8*>(tp_ + 64);             \
        B3 = *reinterpret_cast<const short8*>(tp_ + 96);             \
    }
#define COMPT(E0, E1, E2, E3, t) {                                                 \
        f32x4 pA = {0.f, 0.f, 0.f, 0.f};                                           \
        f32x4 pB = {0.f, 0.f, 0.f, 0.f};                                           \
        pA = __builtin_amdgcn_mfma_f32_16x16x32_bf16(zh0, E0, pA, 0, 0, 0);        \
        pA = __builtin_amdgcn_mfma_f32_16x16x32_bf16(zh1, E1, pA, 0, 0, 0);        \
        pB = __builtin_amdgcn_mfma_f32_16x16x32_bf16(zh0, E2, pB, 0, 0, 0);        \
        pB = __builtin_amdgcn_mfma_f32_16x16x32_bf16(zh1, E3, pB, 0, 0, 0);        \
        pB = __builtin_amdgcn_mfma_f32_16x16x32_bf16(zl0, E0, pB, 0, 0, 0);        \
        pB = __builtin_amdgcn_mfma_f32_16x16x32_bf16(zl1, E1, pB, 0, 0, 0);        \
        const int code = wbase + (t) * 16 + lc;                                    \
        const float ne_c = sne[wave][(t) * 16 + lc];                               \
        _Pragma("unroll")                                                          \
        for (int r = 0; r < 4; ++r) {                                              \
            float t1 = nzr[r] + ne_c;                                              \
            float d = fmaf(-2.0f, pA[r] + pB[r], t1);                              \
            float m = fminf(d, b2[r]);                                             \
            bool lt = d < b1[r];                                                   \
            b2[r] = lt ? b1[r] : m;                                                \
            k1[r] = lt ? code : k1[r];                                             \
            b1[r] = fminf(d, b1[r]);                                               \
        }                                                                          \
    }

__global__ __launch_bounds__(256, 4) void kargmin_kernel(
    const float* __restrict__ z, const unsigned short* __restrict__ ebhl,
    const float* __restrict__ norms,
    int* __restrict__ idx, unsigned int* __restrict__ counts,
    float* __restrict__ out_idx, float* __restrict__ out_oh,
    unsigned int* __restrict__ fixcnt, int* __restrict__ fixlist)
{
    __shared__ float szt[16][68];       // z tile: 16 pts x 64 dims
    __shared__ float snz[16];           // np-replicated ||z||^2
    __shared__ float sne[4][256];       // per-wave code norms
    __shared__ float mb1[4][16], mb2[4][16];
    __shared__ int   mk1[4][16];
    __shared__ int   sk[16];

    const int tid = threadIdx.x;
    const int wave = tid >> 6;
    const int lane = tid & 63;
    const int lc = lane & 15;       // A row (point) / B col (code-in-tile)
    const int rg = lane >> 4;       // K-chunk group 0..3
    const int pbase = blockIdx.x * 16;
    const int b = pbase >> 10;
    const int hw0 = pbase & 1023;

    // stage z tile (16 pts x 64 dims)
    {
        const int pt = tid & 15, c0 = tid >> 4;
#pragma unroll
        for (int cg = 0; cg < 4; ++cg) {
            int c = cg * 16 + c0;
            szt[pt][c] = z[((b * E_DIM + c) << 10) + hw0 + pt];
        }
    }
    // stage this wave's 256 code norms
    *reinterpret_cast<float4*>(&sne[wave][lane * 4]) =
        *reinterpret_cast<const float4*>(norms + wave * 256 + lane * 4);
    __syncthreads();
    if (tid < 16) snz[tid] = np_sum64_sq(&szt[tid][0]);
    __syncthreads();

    // A-fragments (z): lane row = lc, K-chunks per rg
    float4 zv0 = *reinterpret_cast<const float4*>(&szt[lc][rg * 8]);
    float4 zv1 = *reinterpret_cast<const float4*>(&szt[lc][rg * 8 + 4]);
    float4 zv2 = *reinterpret_cast<const float4*>(&szt[lc][32 + rg * 8]);
    float4 zv3 = *reinterpret_cast<const float4*>(&szt[lc][32 + rg * 8 + 4]);
    float zt0[8] = {zv0.x, zv0.y, zv0.z, zv0.w, zv1.x, zv1.y, zv1.z, zv1.w};
    float zt1[8] = {zv2.x, zv2.y, zv2.z, zv2.w, zv3.x, zv3.y, zv3.z, zv3.w};
    short8 zh0, zl0, zh1, zl1;
#pragma unroll
    for (int j = 0; j < 8; ++j) {
        unsigned short h0 = rn_bf16(zt0[j]);
        zh0[j] = (short)h0;
        zl0[j] = (short)rn_bf16(zt0[j] - bf16_to_f(h0));
        unsigned short h1 = rn_bf16(zt1[j]);
        zh1[j] = (short)h1;
        zl1[j] = (short)rn_bf16(zt1[j] - bf16_to_f(h1));
    }

    float nzr[4];
#pragma unroll
    for (int r = 0; r < 4; ++r) nzr[r] = snz[rg * 4 + r];

    // wave's code stream: codes wbase + t*16 + lc, t = 0..15
    const int wbase = wave * 256;
    const unsigned short* ep = ebhl + (size_t)(wbase + lc) * 128 + rg * 8;

    float b1[4] = {3.4028235e38f, 3.4028235e38f, 3.4028235e38f, 3.4028235e38f};
    float b2[4] = {3.4028235e38f, 3.4028235e38f, 3.4028235e38f, 3.4028235e38f};
    int k1[4] = {0, 0, 0, 0};

    short8 A0, A1, A2, A3, B0, B1, B2, B3;
    LOADT(A0, A1, A2, A3, 0);
    LOADT(B0, B1, B2, B3, 1);
#pragma unroll
    for (int t = 0; t < 16; t += 2) {
        COMPT(A0, A1, A2, A3, t);
        if (t + 2 < 16) LOADT(A0, A1, A2, A3, t + 2);
        COMPT(B0, B1, B2, B3, t + 1);
        if (t + 3 < 16) LOADT(B0, B1, B2, B3, t + 3);
    }

    // intra-wave top-2 merge across the 16 code-column lanes
#pragma unroll
    for (int off = 1; off < 16; off <<= 1) {
#pragma unroll
        for (int r = 0; r < 4; ++r) {
            float ob1 = __shfl_xor(b1[r], off, 64);
            float ob2 = __shfl_xor(b2[r], off, 64);
            int   ok1 = __shfl_xor(k1[r], off, 64);
            float nb2 = fminf(fmaxf(b1[r], ob1), fminf(b2[r], ob2));
            if (ob1 < b1[r] || (ob1 == b1[r] && ok1 < k1[r])) { b1[r] = ob1; k1[r] = ok1; }
            b2[r] = nb2;
        }
    }
    if (lc == 0) {
#pragma unroll
        for (int r = 0; r < 4; ++r) {
            mb1[wave][rg * 4 + r] = b1[r];
            mb2[wave][rg * 4 + r] = b2[r];
            mk1[wave][rg * 4 + r] = k1[r];
        }
    }
    __syncthreads();

    // cross-wave merge + outputs (one thread per point row)
    if (tid < 16) {
        const int row = tid;
        float Bb1 = mb1[0][row], Bb2 = mb2[0][row];
        int K = mk1[0][row];
#pragma unroll
        for (int w = 1; w < 4; ++w) {
            float ob1 = mb1[w][row], ob2 = mb2[w][row];
            int ok = mk1[w][row];
            if (ob1 < Bb1 || (ob1 == Bb1 && ok < K)) {
                Bb2 = fminf(Bb1, ob2); Bb1 = ob1; K = ok;
            } else {
                Bb2 = fminf(Bb2, ob1);
            }
        }
        const int p = pbase + row;
        idx[p] = K;
        out_idx[p] = (float)K;
        atomicAdd(&counts[K], 1u);
        sk[row] = K;
        float gap = Bb2 - Bb1;
        if (gap < 4e-5f || (Bb1 >= 128.f && gap < 6.5e-5f)) {
            unsigned int slot = atomicAdd(fixcnt, 1u);
            if (slot < FIXCAP) fixlist[slot] = p;
        }
    }
    __syncthreads();

    // fused one-hot fill: 16 rows x 1024 cols, fully coalesced float4 stores
    {
        const int col = tid << 2;
#pragma unroll
        for (int r16 = 0; r16 < 16; ++r16) {
            int k = sk[r16];
            float4 v;
            v.x = (col + 0 == k) ? 1.f : 0.f;
            v.y = (col + 1 == k) ? 1.f : 0.f;
            v.z = (col + 2 == k) ? 1.f : 0.f;
            v.w = (col + 3 == k) ? 1.f : 0.f;
            *reinterpret_cast<float4*>(
                &out_oh[(size_t)(pbase + r16) * N_E + col]) = v;
        }
    }
}

// Phase B: replicated-fp32-quantized exact re-resolution of flagged points.
// Patches idx, out_idx, counts, AND the fused one-hot row.
__global__ __launch_bounds__(256) void kfix_kernel(
    const float* __restrict__ z, const float* __restrict__ emb,
    const float* __restrict__ norms,
    int* __restrict__ idx, unsigned int* __restrict__ counts,
    float* __restrict__ out_idx, float* __restrict__ out_oh,
    const unsigned int* __restrict__ fixcnt,
    const int* __restrict__ fixlist)
{
    __shared__ float sd[256];
    __shared__ int   si[256];
    unsigned int n = *fixcnt;
    if (n > FIXCAP) n = FIXCAP;
    for (unsigned int it = blockIdx.x; it < n; it += gridDim.x) {
        __syncthreads();
        const int p = fixlist[it];
        const int b = p >> 10, hw = p & 1023;
        float zr[E_DIM];
#pragma unroll
        for (int c = 0; c < E_DIM; ++c)
            zr[c] = z[((b * E_DIM + c) << 10) + hw];
        const float nz = np_sum64_sq(zr);

        const int t = threadIdx.x;
        const float* e0 = emb + (size_t)t * E_DIM;
        const float* e1 = e0 + 256 * E_DIM;
        const float* e2 = e1 + 256 * E_DIM;
        const float* e3 = e2 + 256 * E_DIM;
        double a0 = 0.0, a1 = 0.0, a2 = 0.0, a3 = 0.0;
#pragma unroll
        for (int c = 0; c < E_DIM; ++c) {
            const double zv = (double)zr[c];
            a0 += (double)e0[c] * zv;
            a1 += (double)e1[c] * zv;
            a2 += (double)e2[c] * zv;
            a3 += (double)e3[c] * zv;
        }
        float d0, d1, d2, d3;
        {
#pragma clang fp contract(off)
            float t0 = nz + norms[t];
            float t1 = nz + norms[t + 256];
            float t2 = nz + norms[t + 512];
            float t3 = nz + norms[t + 768];
            d0 = t0 - 2.0f * (float)a0;
            d1 = t1 - 2.0f * (float)a1;
            d2 = t2 - 2.0f * (float)a2;
            d3 = t3 - 2.0f * (float)a3;
        }
        float best = d0; int bestk = t;
        if (d1 < best) { best = d1; bestk = t + 256; }
        if (d2 < best) { best = d2; bestk = t + 512; }
        if (d3 < best) { best = d3; bestk = t + 768; }

        sd[t] = best; si[t] = bestk;
        __syncthreads();
        for (int off = 128; off > 0; off >>= 1) {
            if (t < off) {
                float ob = sd[t + off]; int ok = si[t + off];
                if (ob < sd[t] || (ob == sd[t] && ok < si[t])) {
                    sd[t] = ob; si[t] = ok;
                }
            }
            __syncthreads();
        }
        if (t == 0) {
            int newk = si[0], oldk = idx[p];
            if (newk != oldk) {
                idx[p] = newk;
                out_idx[p] = (float)newk;
                atomicSub(&counts[oldk], 1u);
                atomicAdd(&counts[newk], 1u);
                out_oh[(size_t)p * N_E + oldk] = 0.f;
                out_oh[(size_t)p * N_E + newk] = 1.f;
            }
        }
    }
}

// gather z_q (B,C,H,W) + fused loss partial: loss = 1.25 * mean((z_q - z)^2)
__global__ void kzq_kernel(const float* __restrict__ z, const float* __restrict__ emb,
                           const int* __restrict__ idx,
                           float* __restrict__ zq_out, float* __restrict__ loss_accum)
{
    int gid = blockIdx.x * blockDim.x + threadIdx.x;
    int f = gid << 2;
    int hw = f & 1023;
    int bc = f >> 10;
    int c = bc & 63;
    int b = bc >> 6;
    int p = (b << 10) + hw;
    int4 i4 = *reinterpret_cast<const int4*>(&idx[p]);
    float4 zv = *reinterpret_cast<const float4*>(&z[f]);
    float4 q;
    q.x = emb[(size_t)i4.x * E_DIM + c];
    q.y = emb[(size_t)i4.y * E_DIM + c];
    q.z = emb[(size_t)i4.z * E_DIM + c];
    q.w = emb[(size_t)i4.w * E_DIM + c];
    *reinterpret_cast<float4*>(&zq_out[f]) = q;
    float dx = q.x - zv.x, dy = q.y - zv.y, dz = q.z - zv.z, dw = q.w - zv.w;
    float ssum = dx * dx + dy * dy + dz * dz + dw * dw;
#pragma unroll
    for (int off = 32; off > 0; off >>= 1) ssum += __shfl_down(ssum, off, 64);
    __shared__ float wsum[4];
    int lane = threadIdx.x & 63, wid = threadIdx.x >> 6;
    if (lane == 0) wsum[wid] = ssum;
    __syncthreads();
    if (threadIdx.x == 0)
        atomicAdd(loss_accum, wsum[0] + wsum[1] + wsum[2] + wsum[3]);
}

__global__ void kfin_kernel(const unsigned int* __restrict__ counts,
                            const float* __restrict__ loss_accum,
                            float* __restrict__ out_loss, float* __restrict__ out_perp)
{
    int k = threadIdx.x;
    float em = (float)counts[k] / (float)N_PTS;
    float v = em * logf(em + 1e-10f);
#pragma unroll
    for (int off = 32; off > 0; off >>= 1) v += __shfl_down(v, off, 64);
    __shared__ float sb[16];
    int lane = k & 63, wid = k >> 6;
    if (lane == 0) sb[wid] = v;
    __syncthreads();
    if (k == 0) {
        float ssum = 0.f;
#pragma unroll
        for (int i = 0; i < 16; ++i) ssum += sb[i];
        *out_perp = expf(-ssum);
        *out_loss = 1.25f * (*loss_accum) / 2097152.f;
    }
}

extern "C" void kernel_launch(void* const* d_in, const int* in_sizes, int n_in,
                              void* d_out, int out_size, void* d_ws, size_t ws_size,
                              hipStream_t stream) {
    const float* z   = (const float*)d_in[0];
    const float* emb = (const float*)d_in[1];
    float* out = (float*)d_out;

    float* out_loss = out;
    float* out_zq   = out + OFF_ZQ;
    float* out_perp = out + OFF_PERP;
    float* out_oh   = out + OFF_OH;
    float* out_idx  = out + OFF_IDX;

    char* ws = (char*)d_ws;
    float*          loss_accum = (float*)(ws + WS_LOSS);
    unsigned int*   ws_head    = (unsigned int*)(ws + WS_LOSS);
    unsigned int*   fixcnt     = (unsigned int*)(ws + WS_FIXCNT);
    unsigned int*   counts     = (unsigned int*)(ws + WS_COUNTS);
    float*          norms      = (float*)(ws + WS_NORMS);
    int*            idx        = (int*)(ws + WS_IDX);
    int*            fixlist    = (int*)(ws + WS_FIXLIST);
    unsigned short* ebhl       = (unsigned short*)(ws + WS_EBHL);

    eprep_kernel<<<(N_E + 255) / 256, 256, 0, stream>>>(emb, ebhl, norms,
                                                        ws_head, counts);
    kargmin_kernel<<<N_PTS / 16, 256, 0, stream>>>(z, ebhl, norms, idx, counts,
                                                   out_idx, out_oh, fixcnt, fixlist);
    kfix_kernel<<<512, 256, 0, stream>>>(z, emb, norms, idx, counts, out_idx,
                                         out_oh, fixcnt, fixlist);
    kzq_kernel<<<2097152 / 4 / 256, 256, 0, stream>>>(z, emb, idx, out_zq, loss_accum);
    kfin_kernel<<<1, 1024, 0, stream>>>(counts, loss_accum, out_loss, out_perp);
}

// Round 7
// 165.588 us; speedup vs baseline: 1.0431x; 1.0431x over previous
//
#include <hip/hip_runtime.h>

#define E_DIM 64
#define N_E   1024
#define N_PTS 32768

// d_out layout (floats):
#define OFF_ZQ   1
#define OFF_PERP 2097153
#define OFF_OH   2097154
#define OFF_IDX  35651586

// d_ws layout (bytes):
#define WS_LOSS    0        // float
#define WS_FIXCNT  4        // uint
#define WS_COUNTS  256      // uint[1024]
#define WS_NORMS   8192     // float[1024]        (ne, from eprep)
#define WS_IDX     16384    // int[32768]         (ends 147456)
#define WS_FIXLIST 147456   // int[8192]          (ends 180224)
#define WS_EBHL    311296   // ushort[1024*128]   hi[64],lo[64] per code
#define FIXCAP     8192

typedef __attribute__((ext_vector_type(8))) short short8;
typedef __attribute__((ext_vector_type(4))) float f32x4;
typedef __attribute__((ext_vector_type(2))) float f32x2;

// numpy pairwise_sum replication for n=64 over squares (fp32, no contraction)
__device__ __forceinline__ float np_sum64_sq(const float* a) {
#pragma clang fp contract(off)
    float r0 = a[0] * a[0];
    float r1 = a[1] * a[1];
    float r2 = a[2] * a[2];
    float r3 = a[3] * a[3];
    float r4 = a[4] * a[4];
    float r5 = a[5] * a[5];
    float r6 = a[6] * a[6];
    float r7 = a[7] * a[7];
#pragma unroll
    for (int m = 1; m < 8; ++m) {
        r0 += a[8 * m + 0] * a[8 * m + 0];
        r1 += a[8 * m + 1] * a[8 * m + 1];
        r2 += a[8 * m + 2] * a[8 * m + 2];
        r3 += a[8 * m + 3] * a[8 * m + 3];
        r4 += a[8 * m + 4] * a[8 * m + 4];
        r5 += a[8 * m + 5] * a[8 * m + 5];
        r6 += a[8 * m + 6] * a[8 * m + 6];
        r7 += a[8 * m + 7] * a[8 * m + 7];
    }
    return ((r0 + r1) + (r2 + r3)) + ((r4 + r5) + (r6 + r7));
}

__device__ __forceinline__ unsigned short rn_bf16(float f) {
    unsigned int u = __float_as_uint(f);
    return (unsigned short)((u + 0x7FFFu + ((u >> 16) & 1u)) >> 16);
}
__device__ __forceinline__ float bf16_to_f(unsigned short h) {
    return __uint_as_float(((unsigned int)h) << 16);
}

// prep: codebook -> hi/lo bf16 + ||e||^2; block 0 also zeroes ws accumulators
__global__ void eprep_kernel(const float* __restrict__ emb,
                             unsigned short* __restrict__ ebhl,
                             float* __restrict__ norms,
                             unsigned int* __restrict__ ws_head,
                             unsigned int* __restrict__ counts) {
    int k = blockIdx.x * blockDim.x + threadIdx.x;
    if (blockIdx.x == 0) {
        if (threadIdx.x < 2) ws_head[threadIdx.x] = 0u;
        *reinterpret_cast<uint4*>(&counts[threadIdx.x * 4]) = make_uint4(0u, 0u, 0u, 0u);
    }
    if (k >= N_E) return;
    float er[E_DIM];
    const float4* e4 = reinterpret_cast<const float4*>(emb) + (size_t)k * (E_DIM / 4);
#pragma unroll
    for (int i = 0; i < E_DIM / 4; ++i)
        *reinterpret_cast<float4*>(&er[i * 4]) = e4[i];
    norms[k] = np_sum64_sq(er);
    unsigned int* rh = (unsigned int*)(ebhl + (size_t)k * 128);
    unsigned int* rl = rh + 32;
#pragma unroll
    for (int c = 0; c < E_DIM; c += 2) {
        unsigned short h0 = rn_bf16(er[c]);
        unsigned short h1 = rn_bf16(er[c + 1]);
        unsigned short l0 = rn_bf16(er[c] - bf16_to_f(h0));
        unsigned short l1 = rn_bf16(er[c + 1] - bf16_to_f(h1));
        rh[c / 2] = (unsigned int)h0 | ((unsigned int)h1 << 16);
        rl[c / 2] = (unsigned int)l0 | ((unsigned int)l1 << 16);
    }
}

// Phase A: MFMA split-bf16 distance + argmin.
// 1024 blocks x 256 thr (4 waves). Block = 32 points.
// Wave w: point-group g=w&1 (16 pts), code-half h=w>>1 (512 codes, 32 tiles).
#define LOADT(B0, B1, B2, B3, t) {                                   \
        const unsigned short* tp_ = ep + (size_t)(t) * 2048;         \
        B0 = *reinterpret_cast<const short8*>(tp_);                  \
        B1 = *reinterpret_cast<const short8*>(tp_ + 32);             \
        B2 = *reinterpret_cast<const short8*>(tp_ + 64);             \
        B3 = *reinterpret_cast<const short8*>(tp_ + 96);             \
    }
#define COMPT(E0, E1, E2, E3, t) {                                                 \
        f32x4 pA = {0.f, 0.f, 0.f, 0.f};                                           \
        f32x4 pB = {0.f, 0.f, 0.f, 0.f};                                           \
        pA = __builtin_amdgcn_mfma_f32_16x16x32_bf16(zh0, E0, pA, 0, 0, 0);        \
        pA = __builtin_amdgcn_mfma_f32_16x16x32_bf16(zh1, E1, pA, 0, 0, 0);        \
        pB = __builtin_amdgcn_mfma_f32_16x16x32_bf16(zh0, E2, pB, 0, 0, 0);        \
        pB = __builtin_amdgcn_mfma_f32_16x16x32_bf16(zh1, E3, pB, 0, 0, 0);        \
        pB = __builtin_amdgcn_mfma_f32_16x16x32_bf16(zl0, E0, pB, 0, 0, 0);        \
        pB = __builtin_amdgcn_mfma_f32_16x16x32_bf16(zl1, E1, pB, 0, 0, 0);        \
        const int code = wbase + (t) * 16 + lc;                                    \
        const float ne_c = snep[(t) * 16 + lc];                                    \
        _Pragma("unroll")                                                          \
        for (int r = 0; r < 4; ++r) {                                              \
            float t1 = nzr[r] + ne_c;                                              \
            float d = fmaf(-2.0f, pA[r] + pB[r], t1);                              \
            float m = fminf(d, b2[r]);                                             \
            bool lt = d < b1[r];                                                   \
            b2[r] = lt ? b1[r] : m;                                                \
            k1[r] = lt ? code : k1[r];                                             \
            b1[r] = fminf(d, b1[r]);                                               \
        }                                                                          \
    }

__global__ __launch_bounds__(256, 4) void kargmin_kernel(
    const float* __restrict__ z, const unsigned short* __restrict__ ebhl,
    const float* __restrict__ norms,
    int* __restrict__ idx, unsigned int* __restrict__ counts,
    float* __restrict__ out_idx,
    unsigned int* __restrict__ fixcnt, int* __restrict__ fixlist)
{
    __shared__ float szt[32][68];       // z tile: 32 pts x 64 dims
    __shared__ float snz[32];           // np-replicated ||z||^2
    __shared__ float sne[2][512];       // per-half code norms
    __shared__ float mb1[4][16], mb2[4][16];
    __shared__ int   mk1[4][16];

    const int tid = threadIdx.x;
    const int wave = tid >> 6;
    const int lane = tid & 63;
    const int lc = lane & 15;       // A row (point-in-group) / B col (code-in-tile)
    const int rg = lane >> 4;       // K-chunk group 0..3
    const int g = wave & 1;         // point-group
    const int h = wave >> 1;        // code-half
    const int pbase = blockIdx.x * 32;
    const int b = pbase >> 10;
    const int hw0 = pbase & 1023;

    // stage z tile: 32 consecutive pts per c -> full 128B segments
    {
        const int pt = tid & 31, c0 = tid >> 5;   // c0 = 0..7
#pragma unroll
        for (int cg = 0; cg < 8; ++cg) {
            int c = cg * 8 + c0;
            szt[pt][c] = z[((b * E_DIM + c) << 10) + hw0 + pt];
        }
    }
    // stage code norms (both halves, 1024 floats)
    *reinterpret_cast<float4*>(&((float*)sne)[tid * 4]) =
        *reinterpret_cast<const float4*>(norms + tid * 4);
    __syncthreads();
    if (tid < 32) snz[tid] = np_sum64_sq(&szt[tid][0]);
    __syncthreads();

    // A-fragments (z): lane row = g*16+lc, K-chunks per rg
    const int pa = g * 16 + lc;
    float4 zv0 = *reinterpret_cast<const float4*>(&szt[pa][rg * 8]);
    float4 zv1 = *reinterpret_cast<const float4*>(&szt[pa][rg * 8 + 4]);
    float4 zv2 = *reinterpret_cast<const float4*>(&szt[pa][32 + rg * 8]);
    float4 zv3 = *reinterpret_cast<const float4*>(&szt[pa][32 + rg * 8 + 4]);
    float zt0[8] = {zv0.x, zv0.y, zv0.z, zv0.w, zv1.x, zv1.y, zv1.z, zv1.w};
    float zt1[8] = {zv2.x, zv2.y, zv2.z, zv2.w, zv3.x, zv3.y, zv3.z, zv3.w};
    short8 zh0, zl0, zh1, zl1;
#pragma unroll
    for (int j = 0; j < 8; ++j) {
        unsigned short h0 = rn_bf16(zt0[j]);
        zh0[j] = (short)h0;
        zl0[j] = (short)rn_bf16(zt0[j] - bf16_to_f(h0));
        unsigned short h1 = rn_bf16(zt1[j]);
        zh1[j] = (short)h1;
        zl1[j] = (short)rn_bf16(zt1[j] - bf16_to_f(h1));
    }

    float nzr[4];
#pragma unroll
    for (int r = 0; r < 4; ++r) nzr[r] = snz[g * 16 + rg * 4 + r];

    // wave's code stream: codes wbase + t*16 + lc, t = 0..31
    const int wbase = h * 512;
    const unsigned short* ep = ebhl + (size_t)(wbase + lc) * 128 + rg * 8;
    const float* snep = &sne[h][0];

    float b1[4] = {3.4028235e38f, 3.4028235e38f, 3.4028235e38f, 3.4028235e38f};
    float b2[4] = {3.4028235e38f, 3.4028235e38f, 3.4028235e38f, 3.4028235e38f};
    int k1[4] = {0, 0, 0, 0};

    short8 A0, A1, A2, A3, B0, B1, B2, B3;
    LOADT(A0, A1, A2, A3, 0);
    LOADT(B0, B1, B2, B3, 1);
#pragma unroll 4
    for (int t = 0; t < 32; t += 2) {
        COMPT(A0, A1, A2, A3, t);
        LOADT(A0, A1, A2, A3, (t + 2) & 31);
        COMPT(B0, B1, B2, B3, t + 1);
        LOADT(B0, B1, B2, B3, (t + 3) & 31);
    }

    // intra-wave top-2 merge across the 16 code-column lanes
#pragma unroll
    for (int off = 1; off < 16; off <<= 1) {
#pragma unroll
        for (int r = 0; r < 4; ++r) {
            float ob1 = __shfl_xor(b1[r], off, 64);
            float ob2 = __shfl_xor(b2[r], off, 64);
            int   ok1 = __shfl_xor(k1[r], off, 64);
            float nb2 = fminf(fmaxf(b1[r], ob1), fminf(b2[r], ob2));
            if (ob1 < b1[r] || (ob1 == b1[r] && ok1 < k1[r])) { b1[r] = ob1; k1[r] = ok1; }
            b2[r] = nb2;
        }
    }
    if (lc == 0) {
#pragma unroll
        for (int r = 0; r < 4; ++r) {
            mb1[wave][rg * 4 + r] = b1[r];
            mb2[wave][rg * 4 + r] = b2[r];
            mk1[wave][rg * 4 + r] = k1[r];
        }
    }
    __syncthreads();

    // cross-wave (code-half) merge + outputs: one thread per point row
    if (tid < 32) {
        const int row = tid;          // 0..31 -> point pbase+row
        const int pg = row >> 4;      // point-group
        const int r16 = row & 15;
        // wave pg holds codes 0..511 (lower indices): ties prefer it
        float Bb1 = mb1[pg][r16], Bb2 = mb2[pg][r16];
        int K = mk1[pg][r16];
        {
            float ob1 = mb1[pg + 2][r16], ob2 = mb2[pg + 2][r16];
            int ok = mk1[pg + 2][r16];
            if (ob1 < Bb1) { Bb2 = fminf(Bb1, ob2); Bb1 = ob1; K = ok; }
            else           { Bb2 = fminf(Bb2, ob1); }
        }
        const int p = pbase + row;
        idx[p] = K;
        out_idx[p] = (float)K;
        atomicAdd(&counts[K], 1u);
        float gap = Bb2 - Bb1;
        if (gap < 4e-5f || (Bb1 >= 128.f && gap < 6.5e-5f)) {
            unsigned int slot = atomicAdd(fixcnt, 1u);
            if (slot < FIXCAP) fixlist[slot] = p;
        }
    }
}

// Phase B: replicated-fp32-quantized exact re-resolution of flagged points.
__global__ __launch_bounds__(256) void kfix_kernel(
    const float* __restrict__ z, const float* __restrict__ emb,
    const float* __restrict__ norms,
    int* __restrict__ idx, unsigned int* __restrict__ counts,
    float* __restrict__ out_idx,
    const unsigned int* __restrict__ fixcnt,
    const int* __restrict__ fixlist)
{
    __shared__ float sd[256];
    __shared__ int   si[256];
    unsigned int n = *fixcnt;
    if (n > FIXCAP) n = FIXCAP;
    for (unsigned int it = blockIdx.x; it < n; it += gridDim.x) {
        __syncthreads();
        const int p = fixlist[it];
        const int b = p >> 10, hw = p & 1023;
        float zr[E_DIM];
#pragma unroll
        for (int c = 0; c < E_DIM; ++c)
            zr[c] = z[((b * E_DIM + c) << 10) + hw];
        const float nz = np_sum64_sq(zr);

        const int t = threadIdx.x;
        const float* e0 = emb + (size_t)t * E_DIM;
        const float* e1 = e0 + 256 * E_DIM;
        const float* e2 = e1 + 256 * E_DIM;
        const float* e3 = e2 + 256 * E_DIM;
        double a0 = 0.0, a1 = 0.0, a2 = 0.0, a3 = 0.0;
#pragma unroll
        for (int c = 0; c < E_DIM; ++c) {
            const double zv = (double)zr[c];
            a0 += (double)e0[c] * zv;
            a1 += (double)e1[c] * zv;
            a2 += (double)e2[c] * zv;
            a3 += (double)e3[c] * zv;
        }
        float d0, d1, d2, d3;
        {
#pragma clang fp contract(off)
            float t0 = nz + norms[t];
            float t1 = nz + norms[t + 256];
            float t2 = nz + norms[t + 512];
            float t3 = nz + norms[t + 768];
            d0 = t0 - 2.0f * (float)a0;
            d1 = t1 - 2.0f * (float)a1;
            d2 = t2 - 2.0f * (float)a2;
            d3 = t3 - 2.0f * (float)a3;
        }
        float best = d0; int bestk = t;
        if (d1 < best) { best = d1; bestk = t + 256; }
        if (d2 < best) { best = d2; bestk = t + 512; }
        if (d3 < best) { best = d3; bestk = t + 768; }

        sd[t] = best; si[t] = bestk;
        __syncthreads();
        for (int off = 128; off > 0; off >>= 1) {
            if (t < off) {
                float ob = sd[t + off]; int ok = si[t + off];
                if (ob < sd[t] || (ob == sd[t] && ok < si[t])) {
                    sd[t] = ob; si[t] = ok;
                }
            }
            __syncthreads();
        }
        if (t == 0) {
            int newk = si[0], oldk = idx[p];
            if (newk != oldk) {
                idx[p] = newk;
                out_idx[p] = (float)newk;
                atomicSub(&counts[oldk], 1u);
                atomicAdd(&counts[newk], 1u);
            }
        }
    }
}

// Fused post: blocks [0,2048) one-hot (8B-aligned f32x2 nontemporal stores);
// blocks [2048,4096) z_q gather + loss partial (aligned scalar nt stores).
__global__ __launch_bounds__(256) void kpost_kernel(
    const float* __restrict__ z, const float* __restrict__ emb,
    const int* __restrict__ idx,
    float* __restrict__ oh, float* __restrict__ zq_out,
    float* __restrict__ loss_accum)
{
    if (blockIdx.x < 2048) {
        __shared__ int sk[16];
        const int row0 = blockIdx.x * 16;
        if (threadIdx.x < 16) sk[threadIdx.x] = idx[row0 + threadIdx.x];
        __syncthreads();
        const int t = threadIdx.x;
#pragma unroll
        for (int r = 0; r < 16; ++r) {
            const int k = sk[r];
            f32x2* rp = reinterpret_cast<f32x2*>(&oh[(size_t)(row0 + r) * N_E]);
            f32x2 v0 = {(2 * t     == k) ? 1.f : 0.f, (2 * t + 1   == k) ? 1.f : 0.f};
            f32x2 v1 = {(2 * t + 512 == k) ? 1.f : 0.f, (2 * t + 513 == k) ? 1.f : 0.f};
            __builtin_nontemporal_store(v0, rp + t);
            __builtin_nontemporal_store(v1, rp + t + 256);
        }
    } else {
        int gid = (blockIdx.x - 2048) * blockDim.x + threadIdx.x;
        int f = gid << 2;
        int hw = f & 1023;
        int bc = f >> 10;
        int c = bc & 63;
        int b = bc >> 6;
        int p = (b << 10) + hw;
        int4 i4 = *reinterpret_cast<const int4*>(&idx[p]);
        float4 zv = *reinterpret_cast<const float4*>(&z[f]);
        float4 q;
        q.x = emb[(size_t)i4.x * E_DIM + c];
        q.y = emb[(size_t)i4.y * E_DIM + c];
        q.z = emb[(size_t)i4.z * E_DIM + c];
        q.w = emb[(size_t)i4.w * E_DIM + c];
        __builtin_nontemporal_store(q.x, &zq_out[f]);
        __builtin_nontemporal_store(q.y, &zq_out[f + 1]);
        __builtin_nontemporal_store(q.z, &zq_out[f + 2]);
        __builtin_nontemporal_store(q.w, &zq_out[f + 3]);
        float dx = q.x - zv.x, dy = q.y - zv.y, dz = q.z - zv.z, dw = q.w - zv.w;
        float ssum = dx * dx + dy * dy + dz * dz + dw * dw;
#pragma unroll
        for (int off = 32; off > 0; off >>= 1) ssum += __shfl_down(ssum, off, 64);
        __shared__ float wsum[4];
        int lane = threadIdx.x & 63, wid = threadIdx.x >> 6;
        if (lane == 0) wsum[wid] = ssum;
        __syncthreads();
        if (threadIdx.x == 0)
            atomicAdd(loss_accum, wsum[0] + wsum[1] + wsum[2] + wsum[3]);
    }
}

__global__ void kfin_kernel(const unsigned int* __restrict__ counts,
                            const float* __restrict__ loss_accum,
                            float* __restrict__ out_loss, float* __restrict__ out_perp)
{
    int k = threadIdx.x;
    float em = (float)counts[k] / (float)N_PTS;
    float v = em * logf(em + 1e-10f);
#pragma unroll
    for (int off = 32; off > 0; off >>= 1) v += __shfl_down(v, off, 64);
    __shared__ float sb[16];
    int lane = k & 63, wid = k >> 6;
    if (lane == 0) sb[wid] = v;
    __syncthreads();
    if (k == 0) {
        float ssum = 0.f;
#pragma unroll
        for (int i = 0; i < 16; ++i) ssum += sb[i];
        *out_perp = expf(-ssum);
        *out_loss = 1.25f * (*loss_accum) / 2097152.f;
    }
}

extern "C" void kernel_launch(void* const* d_in, const int* in_sizes, int n_in,
                              void* d_out, int out_size, void* d_ws, size_t ws_size,
                              hipStream_t stream) {
    const float* z   = (const float*)d_in[0];
    const float* emb = (const float*)d_in[1];
    float* out = (float*)d_out;

    float* out_loss = out;
    float* out_zq   = out + OFF_ZQ;
    float* out_perp = out + OFF_PERP;
    float* out_oh   = out + OFF_OH;
    float* out_idx  = out + OFF_IDX;

    char* ws = (char*)d_ws;
    float*          loss_accum = (float*)(ws + WS_LOSS);
    unsigned int*   ws_head    = (unsigned int*)(ws + WS_LOSS);
    unsigned int*   fixcnt     = (unsigned int*)(ws + WS_FIXCNT);
    unsigned int*   counts     = (unsigned int*)(ws + WS_COUNTS);
    float*          norms      = (float*)(ws + WS_NORMS);
    int*            idx        = (int*)(ws + WS_IDX);
    int*            fixlist    = (int*)(ws + WS_FIXLIST);
    unsigned short* ebhl       = (unsigned short*)(ws + WS_EBHL);

    eprep_kernel<<<(N_E + 255) / 256, 256, 0, stream>>>(emb, ebhl, norms,
                                                        ws_head, counts);
    kargmin_kernel<<<N_PTS / 32, 256, 0, stream>>>(z, ebhl, norms, idx, counts,
                                                   out_idx, fixcnt, fixlist);
    kfix_kernel<<<512, 256, 0, stream>>>(z, emb, norms, idx, counts, out_idx,
                                         fixcnt, fixlist);
    kpost_kernel<<<4096, 256, 0, stream>>>(z, emb, idx, out_oh, out_zq, loss_accum);
    kfin_kernel<<<1, 1024, 0, stream>>>(counts, loss_accum, out_loss, out_perp);
}

// Round 8
// 139.830 us; speedup vs baseline: 1.2352x; 1.1842x over previous
//
#include <hip/hip_runtime.h>

#define E_DIM 64
#define N_E   1024
#define N_PTS 32768

// d_out layout (floats):
#define OFF_ZQ   1
#define OFF_PERP 2097153
#define OFF_OH   2097154
#define OFF_IDX  35651586

// d_ws layout (bytes):
#define WS_LOSS    0        // float
#define WS_FIXCNT  4        // uint
#define WS_COUNTS  256      // uint[1024]
#define WS_NORMS   8192     // float[1024]        (ne, from eprep)
#define WS_IDX     16384    // int[32768]         (ends 147456)
#define WS_FIXLIST 147456   // int[8192]          (ends 180224)
#define WS_EBHL    311296   // ushort[1024*128]   hi[64],lo[64] per code
#define FIXCAP     8192

typedef __attribute__((ext_vector_type(8))) short short8;
typedef __attribute__((ext_vector_type(4))) float f32x4;
typedef __attribute__((ext_vector_type(4))) unsigned int u32x4;

// numpy pairwise_sum replication for n=64 over squares (fp32, no contraction)
__device__ __forceinline__ float np_sum64_sq(const float* a) {
#pragma clang fp contract(off)
    float r0 = a[0] * a[0];
    float r1 = a[1] * a[1];
    float r2 = a[2] * a[2];
    float r3 = a[3] * a[3];
    float r4 = a[4] * a[4];
    float r5 = a[5] * a[5];
    float r6 = a[6] * a[6];
    float r7 = a[7] * a[7];
#pragma unroll
    for (int m = 1; m < 8; ++m) {
        r0 += a[8 * m + 0] * a[8 * m + 0];
        r1 += a[8 * m + 1] * a[8 * m + 1];
        r2 += a[8 * m + 2] * a[8 * m + 2];
        r3 += a[8 * m + 3] * a[8 * m + 3];
        r4 += a[8 * m + 4] * a[8 * m + 4];
        r5 += a[8 * m + 5] * a[8 * m + 5];
        r6 += a[8 * m + 6] * a[8 * m + 6];
        r7 += a[8 * m + 7] * a[8 * m + 7];
    }
    return ((r0 + r1) + (r2 + r3)) + ((r4 + r5) + (r6 + r7));
}

__device__ __forceinline__ unsigned short rn_bf16(float f) {
    unsigned int u = __float_as_uint(f);
    return (unsigned short)((u + 0x7FFFu + ((u >> 16) & 1u)) >> 16);
}
__device__ __forceinline__ float bf16_to_f(unsigned short h) {
    return __uint_as_float(((unsigned int)h) << 16);
}

// prep: codebook -> hi/lo bf16 + ||e||^2; block 0 also zeroes ws accumulators
__global__ void eprep_kernel(const float* __restrict__ emb,
                             unsigned short* __restrict__ ebhl,
                             float* __restrict__ norms,
                             unsigned int* __restrict__ ws_head,
                             unsigned int* __restrict__ counts) {
    int k = blockIdx.x * blockDim.x + threadIdx.x;
    if (blockIdx.x == 0) {
        if (threadIdx.x < 2) ws_head[threadIdx.x] = 0u;
        *reinterpret_cast<uint4*>(&counts[threadIdx.x * 4]) = make_uint4(0u, 0u, 0u, 0u);
    }
    if (k >= N_E) return;
    float er[E_DIM];
    const float4* e4 = reinterpret_cast<const float4*>(emb) + (size_t)k * (E_DIM / 4);
#pragma unroll
    for (int i = 0; i < E_DIM / 4; ++i)
        *reinterpret_cast<float4*>(&er[i * 4]) = e4[i];
    norms[k] = np_sum64_sq(er);
    unsigned int* rh = (unsigned int*)(ebhl + (size_t)k * 128);
    unsigned int* rl = rh + 32;
#pragma unroll
    for (int c = 0; c < E_DIM; c += 2) {
        unsigned short h0 = rn_bf16(er[c]);
        unsigned short h1 = rn_bf16(er[c + 1]);
        unsigned short l0 = rn_bf16(er[c] - bf16_to_f(h0));
        unsigned short l1 = rn_bf16(er[c + 1] - bf16_to_f(h1));
        rh[c / 2] = (unsigned int)h0 | ((unsigned int)h1 << 16);
        rl[c / 2] = (unsigned int)l0 | ((unsigned int)l1 << 16);
    }
}

// Phase A: MFMA split-bf16 distance + argmin.
// 1024 blocks x 256 thr (4 waves). Block = 32 points; codebook streamed via
// LDS in 64-code chunks (coalesced GLD + r4-validated XOR-swizzled SWR).
// Wave w computes only code-tile w of each chunk (codes ch*64 + w*16 + lc)
// for all 32 points -> 1/4 the LDS-read traffic of the all-codes scheme.
#define GLD(ch) {                                                             \
        const u32x4* gp = reinterpret_cast<const u32x4*>(ebhl) + (ch) * 1024; \
        _Pragma("unroll")                                                     \
        for (int i = 0; i < 4; ++i) ldreg[i] = gp[tid + i * 256];             \
    }
#define SWR(dstbuf) {                                                         \
        _Pragma("unroll")                                                     \
        for (int i = 0; i < 4; ++i) {                                         \
            int gci = tid + i * 256;                                          \
            int code = gci >> 4, cb = gci & 15;                               \
            int cbs = cb ^ (code & 7);                                        \
            *reinterpret_cast<u32x4*>(                                        \
                &(dstbuf)[(code >> 4) * 2048 + (code & 15) * 128 + cbs * 8])  \
                = ldreg[i];                                                   \
        }                                                                     \
    }

__global__ __launch_bounds__(256) void kargmin_kernel(
    const float* __restrict__ z, const unsigned short* __restrict__ ebhl,
    const float* __restrict__ norms,
    int* __restrict__ idx, unsigned int* __restrict__ counts,
    float* __restrict__ out_idx,
    unsigned int* __restrict__ fixcnt, int* __restrict__ fixlist)
{
    __shared__ float szt[32][68];            // z tile: 32 pts x 64 dims
    __shared__ float snz[32];                // np-replicated ||z||^2
    __shared__ float sne[N_E];               // code norms (4 KB)
    __shared__ unsigned short sbuf[2][8192]; // 2 x 16 KB chunk dbuf (64 codes)
    __shared__ float mb1[4][32], mb2[4][32];
    __shared__ int   mk1[4][32];

    const int tid = threadIdx.x;
    const int wave = tid >> 6;
    const int lane = tid & 63;
    const int lc = lane & 15;       // B col (code-in-tile) / A row lane
    const int rg = lane >> 4;       // K-chunk group 0..3
    const int pbase = blockIdx.x * 32;
    const int b = pbase >> 10;
    const int hw0 = pbase & 1023;

    // stage z tile: 32 consecutive pts per c -> full 128B segments
    {
        const int pt = tid & 31, c0 = tid >> 5;
#pragma unroll
        for (int cg = 0; cg < 8; ++cg) {
            int c = cg * 8 + c0;
            szt[pt][c] = z[((b * E_DIM + c) << 10) + hw0 + pt];
        }
    }
    *reinterpret_cast<float4*>(&sne[tid * 4]) =
        *reinterpret_cast<const float4*>(norms + tid * 4);
    __syncthreads();
    if (tid < 32) snz[tid] = np_sum64_sq(&szt[tid][0]);
    __syncthreads();

    // A-fragments for 2 point-tiles (a=0: pts 0-15, a=1: pts 16-31)
    short8 zh0[2], zh1[2], zl0[2], zl1[2];
#pragma unroll
    for (int a = 0; a < 2; ++a) {
        const int pa = a * 16 + lc;
        float4 zv0 = *reinterpret_cast<const float4*>(&szt[pa][rg * 8]);
        float4 zv1 = *reinterpret_cast<const float4*>(&szt[pa][rg * 8 + 4]);
        float4 zv2 = *reinterpret_cast<const float4*>(&szt[pa][32 + rg * 8]);
        float4 zv3 = *reinterpret_cast<const float4*>(&szt[pa][32 + rg * 8 + 4]);
        float zt0[8] = {zv0.x, zv0.y, zv0.z, zv0.w, zv1.x, zv1.y, zv1.z, zv1.w};
        float zt1[8] = {zv2.x, zv2.y, zv2.z, zv2.w, zv3.x, zv3.y, zv3.z, zv3.w};
#pragma unroll
        for (int j = 0; j < 8; ++j) {
            unsigned short h0 = rn_bf16(zt0[j]);
            zh0[a][j] = (short)h0;
            zl0[a][j] = (short)rn_bf16(zt0[j] - bf16_to_f(h0));
            unsigned short h1 = rn_bf16(zt1[j]);
            zh1[a][j] = (short)h1;
            zl1[a][j] = (short)rn_bf16(zt1[j] - bf16_to_f(h1));
        }
    }

    float nzr[2][4];
#pragma unroll
    for (int a = 0; a < 2; ++a)
#pragma unroll
        for (int r = 0; r < 4; ++r)
            nzr[a][r] = snz[a * 16 + rg * 4 + r];

    float b1[2][4], b2[2][4];
    int k1[2][4];
#pragma unroll
    for (int a = 0; a < 2; ++a)
#pragma unroll
        for (int r = 0; r < 4; ++r) {
            b1[a][r] = 3.4028235e38f; b2[a][r] = 3.4028235e38f; k1[a][r] = 0;
        }

    u32x4 ldreg[4];
    GLD(0);
    SWR(sbuf[0]);
    __syncthreads();

    const int swz = lc & 7;
    for (int ch = 0; ch < 16; ++ch) {
        const int cur = ch & 1;
        if (ch < 15) GLD(ch + 1);

        const unsigned short* sb = &sbuf[cur][wave * 2048 + lc * 128];
        short8 eh0 = *reinterpret_cast<const short8*>(sb + ((rg     ) ^ swz) * 8);
        short8 eh1 = *reinterpret_cast<const short8*>(sb + ((rg + 4 ) ^ swz) * 8);
        short8 el0 = *reinterpret_cast<const short8*>(sb + ((rg + 8 ) ^ swz) * 8);
        short8 el1 = *reinterpret_cast<const short8*>(sb + ((rg + 12) ^ swz) * 8);

        const int code = ch * 64 + wave * 16 + lc;
        const float ne_c = sne[code];
#pragma unroll
        for (int a = 0; a < 2; ++a) {
            f32x4 pA = {0.f, 0.f, 0.f, 0.f};
            f32x4 pB = {0.f, 0.f, 0.f, 0.f};
            pA = __builtin_amdgcn_mfma_f32_16x16x32_bf16(zh0[a], eh0, pA, 0, 0, 0);
            pA = __builtin_amdgcn_mfma_f32_16x16x32_bf16(zh1[a], eh1, pA, 0, 0, 0);
            pB = __builtin_amdgcn_mfma_f32_16x16x32_bf16(zh0[a], el0, pB, 0, 0, 0);
            pB = __builtin_amdgcn_mfma_f32_16x16x32_bf16(zh1[a], el1, pB, 0, 0, 0);
            pB = __builtin_amdgcn_mfma_f32_16x16x32_bf16(zl0[a], eh0, pB, 0, 0, 0);
            pB = __builtin_amdgcn_mfma_f32_16x16x32_bf16(zl1[a], eh1, pB, 0, 0, 0);
#pragma unroll
            for (int r = 0; r < 4; ++r) {
                float t1 = nzr[a][r] + ne_c;
                float d = fmaf(-2.0f, pA[r] + pB[r], t1);
                float m = fminf(d, b2[a][r]);
                bool lt = d < b1[a][r];
                b2[a][r] = lt ? b1[a][r] : m;
                k1[a][r] = lt ? code : k1[a][r];
                b1[a][r] = fminf(d, b1[a][r]);
            }
        }
        if (ch < 15) SWR(sbuf[cur ^ 1]);
        __syncthreads();
    }

    // intra-wave top-2 merge across the 16 code-column lanes
#pragma unroll
    for (int off = 1; off < 16; off <<= 1) {
#pragma unroll
        for (int a = 0; a < 2; ++a)
#pragma unroll
            for (int r = 0; r < 4; ++r) {
                float ob1 = __shfl_xor(b1[a][r], off, 64);
                float ob2 = __shfl_xor(b2[a][r], off, 64);
                int   ok1 = __shfl_xor(k1[a][r], off, 64);
                float nb2 = fminf(fmaxf(b1[a][r], ob1), fminf(b2[a][r], ob2));
                if (ob1 < b1[a][r] || (ob1 == b1[a][r] && ok1 < k1[a][r])) {
                    b1[a][r] = ob1; k1[a][r] = ok1;
                }
                b2[a][r] = nb2;
            }
    }
    if (lc == 0) {
#pragma unroll
        for (int a = 0; a < 2; ++a)
#pragma unroll
            for (int r = 0; r < 4; ++r) {
                mb1[wave][a * 16 + rg * 4 + r] = b1[a][r];
                mb2[wave][a * 16 + rg * 4 + r] = b2[a][r];
                mk1[wave][a * 16 + rg * 4 + r] = k1[a][r];
            }
    }
    __syncthreads();

    // cross-wave (code-tile) merge + outputs: one thread per point row.
    // index-aware compare handles the interleaved code ownership.
    if (tid < 32) {
        const int row = tid;
        float Bb1 = mb1[0][row], Bb2 = mb2[0][row];
        int K = mk1[0][row];
#pragma unroll
        for (int w = 1; w < 4; ++w) {
            float ob1 = mb1[w][row], ob2 = mb2[w][row];
            int ok = mk1[w][row];
            if (ob1 < Bb1 || (ob1 == Bb1 && ok < K)) {
                Bb2 = fminf(Bb1, ob2); Bb1 = ob1; K = ok;
            } else {
                Bb2 = fminf(Bb2, ob1);
            }
        }
        const int p = pbase + row;
        idx[p] = K;
        out_idx[p] = (float)K;
        atomicAdd(&counts[K], 1u);
        float gap = Bb2 - Bb1;
        if (gap < 4e-5f || (Bb1 >= 128.f && gap < 6.5e-5f)) {
            unsigned int slot = atomicAdd(fixcnt, 1u);
            if (slot < FIXCAP) fixlist[slot] = p;
        }
    }
}

// Phase B: replicated-fp32-quantized exact re-resolution of flagged points.
__global__ __launch_bounds__(256) void kfix_kernel(
    const float* __restrict__ z, const float* __restrict__ emb,
    const float* __restrict__ norms,
    int* __restrict__ idx, unsigned int* __restrict__ counts,
    float* __restrict__ out_idx,
    const unsigned int* __restrict__ fixcnt,
    const int* __restrict__ fixlist)
{
    __shared__ float sd[256];
    __shared__ int   si[256];
    unsigned int n = *fixcnt;
    if (n > FIXCAP) n = FIXCAP;
    for (unsigned int it = blockIdx.x; it < n; it += gridDim.x) {
        __syncthreads();
        const int p = fixlist[it];
        const int b = p >> 10, hw = p & 1023;
        float zr[E_DIM];
#pragma unroll
        for (int c = 0; c < E_DIM; ++c)
            zr[c] = z[((b * E_DIM + c) << 10) + hw];
        const float nz = np_sum64_sq(zr);

        const int t = threadIdx.x;
        const float* e0 = emb + (size_t)t * E_DIM;
        const float* e1 = e0 + 256 * E_DIM;
        const float* e2 = e1 + 256 * E_DIM;
        const float* e3 = e2 + 256 * E_DIM;
        double a0 = 0.0, a1 = 0.0, a2 = 0.0, a3 = 0.0;
#pragma unroll
        for (int c = 0; c < E_DIM; ++c) {
            const double zv = (double)zr[c];
            a0 += (double)e0[c] * zv;
            a1 += (double)e1[c] * zv;
            a2 += (double)e2[c] * zv;
            a3 += (double)e3[c] * zv;
        }
        float d0, d1, d2, d3;
        {
#pragma clang fp contract(off)
            float t0 = nz + norms[t];
            float t1 = nz + norms[t + 256];
            float t2 = nz + norms[t + 512];
            float t3 = nz + norms[t + 768];
            d0 = t0 - 2.0f * (float)a0;
            d1 = t1 - 2.0f * (float)a1;
            d2 = t2 - 2.0f * (float)a2;
            d3 = t3 - 2.0f * (float)a3;
        }
        float best = d0; int bestk = t;
        if (d1 < best) { best = d1; bestk = t + 256; }
        if (d2 < best) { best = d2; bestk = t + 512; }
        if (d3 < best) { best = d3; bestk = t + 768; }

        sd[t] = best; si[t] = bestk;
        __syncthreads();
        for (int off = 128; off > 0; off >>= 1) {
            if (t < off) {
                float ob = sd[t + off]; int ok = si[t + off];
                if (ob < sd[t] || (ob == sd[t] && ok < si[t])) {
                    sd[t] = ob; si[t] = ok;
                }
            }
            __syncthreads();
        }
        if (t == 0) {
            int newk = si[0], oldk = idx[p];
            if (newk != oldk) {
                idx[p] = newk;
                out_idx[p] = (float)newk;
                atomicSub(&counts[oldk], 1u);
                atomicAdd(&counts[newk], 1u);
            }
        }
    }
}

// gather z_q (B,C,H,W) + fused loss partial: loss = 1.25 * mean((z_q - z)^2)
__global__ __launch_bounds__(256) void kzq_kernel(
    const float* __restrict__ z, const float* __restrict__ emb,
    const int* __restrict__ idx,
    float* __restrict__ zq_out, float* __restrict__ loss_accum)
{
    int gid = blockIdx.x * blockDim.x + threadIdx.x;
    int f = gid << 2;
    int hw = f & 1023;
    int bc = f >> 10;
    int c = bc & 63;
    int b = bc >> 6;
    int p = (b << 10) + hw;
    int4 i4 = *reinterpret_cast<const int4*>(&idx[p]);
    float4 zv = *reinterpret_cast<const float4*>(&z[f]);
    float4 q;
    q.x = emb[(size_t)i4.x * E_DIM + c];
    q.y = emb[(size_t)i4.y * E_DIM + c];
    q.z = emb[(size_t)i4.z * E_DIM + c];
    q.w = emb[(size_t)i4.w * E_DIM + c];
    __builtin_nontemporal_store(q.x, &zq_out[f]);
    __builtin_nontemporal_store(q.y, &zq_out[f + 1]);
    __builtin_nontemporal_store(q.z, &zq_out[f + 2]);
    __builtin_nontemporal_store(q.w, &zq_out[f + 3]);
    float dx = q.x - zv.x, dy = q.y - zv.y, dz = q.z - zv.z, dw = q.w - zv.w;
    float ssum = dx * dx + dy * dy + dz * dz + dw * dw;
#pragma unroll
    for (int off = 32; off > 0; off >>= 1) ssum += __shfl_down(ssum, off, 64);
    __shared__ float wsum[4];
    int lane = threadIdx.x & 63, wid = threadIdx.x >> 6;
    if (lane == 0) wsum[wid] = ssum;
    __syncthreads();
    if (threadIdx.x == 0)
        atomicAdd(loss_accum, wsum[0] + wsum[1] + wsum[2] + wsum[3]);
}

// one-hot "ones" scatter (buffer pre-zeroed by hipMemsetAsync node)
__global__ void kones_kernel(const int* __restrict__ idx, float* __restrict__ oh)
{
    int p = blockIdx.x * blockDim.x + threadIdx.x;
    if (p < N_PTS)
        oh[(size_t)p * N_E + idx[p]] = 1.0f;
}

__global__ void kfin_kernel(const unsigned int* __restrict__ counts,
                            const float* __restrict__ loss_accum,
                            float* __restrict__ out_loss, float* __restrict__ out_perp)
{
    int k = threadIdx.x;
    float em = (float)counts[k] / (float)N_PTS;
    float v = em * logf(em + 1e-10f);
#pragma unroll
    for (int off = 32; off > 0; off >>= 1) v += __shfl_down(v, off, 64);
    __shared__ float sb[16];
    int lane = k & 63, wid = k >> 6;
    if (lane == 0) sb[wid] = v;
    __syncthreads();
    if (k == 0) {
        float ssum = 0.f;
#pragma unroll
        for (int i = 0; i < 16; ++i) ssum += sb[i];
        *out_perp = expf(-ssum);
        *out_loss = 1.25f * (*loss_accum) / 2097152.f;
    }
}

extern "C" void kernel_launch(void* const* d_in, const int* in_sizes, int n_in,
                              void* d_out, int out_size, void* d_ws, size_t ws_size,
                              hipStream_t stream) {
    const float* z   = (const float*)d_in[0];
    const float* emb = (const float*)d_in[1];
    float* out = (float*)d_out;

    float* out_loss = out;
    float* out_zq   = out + OFF_ZQ;
    float* out_perp = out + OFF_PERP;
    float* out_oh   = out + OFF_OH;
    float* out_idx  = out + OFF_IDX;

    char* ws = (char*)d_ws;
    float*          loss_accum = (float*)(ws + WS_LOSS);
    unsigned int*   ws_head    = (unsigned int*)(ws + WS_LOSS);
    unsigned int*   fixcnt     = (unsigned int*)(ws + WS_FIXCNT);
    unsigned int*   counts     = (unsigned int*)(ws + WS_COUNTS);
    float*          norms      = (float*)(ws + WS_NORMS);
    int*            idx        = (int*)(ws + WS_IDX);
    int*            fixlist    = (int*)(ws + WS_FIXLIST);
    unsigned short* ebhl       = (unsigned short*)(ws + WS_EBHL);

    // one-hot zero-fill at fill-primitive speed (~6.5 TB/s measured)
    hipMemsetAsync(out_oh, 0, (size_t)N_PTS * N_E * sizeof(float), stream);

    eprep_kernel<<<(N_E + 255) / 256, 256, 0, stream>>>(emb, ebhl, norms,
                                                        ws_head, counts);
    kargmin_kernel<<<N_PTS / 32, 256, 0, stream>>>(z, ebhl, norms, idx, counts,
                                                   out_idx, fixcnt, fixlist);
    kfix_kernel<<<512, 256, 0, stream>>>(z, emb, norms, idx, counts, out_idx,
                                         fixcnt, fixlist);
    kzq_kernel<<<2097152 / 4 / 256, 256, 0, stream>>>(z, emb, idx, out_zq, loss_accum);
    kones_kernel<<<N_PTS / 256, 256, 0, stream>>>(idx, out_oh);
    kfin_kernel<<<1, 1024, 0, stream>>>(counts, loss_accum, out_loss, out_perp);
}

// Round 9
// 114.876 us; speedup vs baseline: 1.5035x; 1.2172x over previous
//
#include <hip/hip_runtime.h>

#define E_DIM 64
#define N_E   1024
#define N_PTS 32768

// d_out layout (floats):
#define OFF_ZQ   1
#define OFF_PERP 2097153
#define OFF_OH   2097154
#define OFF_IDX  35651586

// d_ws layout (bytes):
#define WS_LOSS    0        // float
#define WS_FIXCNT  4        // uint
#define WS_COUNTS  256      // uint[1024]
#define WS_NORMS   8192     // float[1024]
#define WS_IDX     16384    // int[32768]        (ends 147456)
#define WS_FIXLIST 147456   // int[8192]         (ends 180224)
#define WS_NZ      180224   // float[32768]      (ends 311296)
#define WS_EBHL    311296   // ushort[1024*128]  hi[64],lo[64] per code
#define FIXCAP     8192

typedef __attribute__((ext_vector_type(8))) short short8;
typedef __attribute__((ext_vector_type(4))) float f32x4;
typedef __attribute__((ext_vector_type(4))) unsigned int u32x4;

// numpy pairwise_sum replication for n=64 over squares (fp32, no contraction)
__device__ __forceinline__ float np_sum64_sq(const float* a) {
#pragma clang fp contract(off)
    float r0 = a[0] * a[0];
    float r1 = a[1] * a[1];
    float r2 = a[2] * a[2];
    float r3 = a[3] * a[3];
    float r4 = a[4] * a[4];
    float r5 = a[5] * a[5];
    float r6 = a[6] * a[6];
    float r7 = a[7] * a[7];
#pragma unroll
    for (int m = 1; m < 8; ++m) {
        r0 += a[8 * m + 0] * a[8 * m + 0];
        r1 += a[8 * m + 1] * a[8 * m + 1];
        r2 += a[8 * m + 2] * a[8 * m + 2];
        r3 += a[8 * m + 3] * a[8 * m + 3];
        r4 += a[8 * m + 4] * a[8 * m + 4];
        r5 += a[8 * m + 5] * a[8 * m + 5];
        r6 += a[8 * m + 6] * a[8 * m + 6];
        r7 += a[8 * m + 7] * a[8 * m + 7];
    }
    return ((r0 + r1) + (r2 + r3)) + ((r4 + r5) + (r6 + r7));
}

__device__ __forceinline__ unsigned short rn_bf16(float f) {
    unsigned int u = __float_as_uint(f);
    return (unsigned short)((u + 0x7FFFu + ((u >> 16) & 1u)) >> 16);
}
__device__ __forceinline__ float bf16_to_f(unsigned short h) {
    return __uint_as_float(((unsigned int)h) << 16);
}

// prep: codebook -> hi/lo bf16 + ||e||^2; block 0 also zeroes ws accumulators
__global__ void eprep_kernel(const float* __restrict__ emb,
                             unsigned short* __restrict__ ebhl,
                             float* __restrict__ norms,
                             unsigned int* __restrict__ ws_head,
                             unsigned int* __restrict__ counts) {
    int k = blockIdx.x * blockDim.x + threadIdx.x;
    if (blockIdx.x == 0) {
        if (threadIdx.x < 2) ws_head[threadIdx.x] = 0u;
        *reinterpret_cast<uint4*>(&counts[threadIdx.x * 4]) = make_uint4(0u, 0u, 0u, 0u);
    }
    if (k >= N_E) return;
    float er[E_DIM];
    const float4* e4 = reinterpret_cast<const float4*>(emb) + (size_t)k * (E_DIM / 4);
#pragma unroll
    for (int i = 0; i < E_DIM / 4; ++i)
        *reinterpret_cast<float4*>(&er[i * 4]) = e4[i];
    norms[k] = np_sum64_sq(er);
    unsigned int* rh = (unsigned int*)(ebhl + (size_t)k * 128);
    unsigned int* rl = rh + 32;
#pragma unroll
    for (int c = 0; c < E_DIM; c += 2) {
        unsigned short h0 = rn_bf16(er[c]);
        unsigned short h1 = rn_bf16(er[c + 1]);
        unsigned short l0 = rn_bf16(er[c] - bf16_to_f(h0));
        unsigned short l1 = rn_bf16(er[c + 1] - bf16_to_f(h1));
        rh[c / 2] = (unsigned int)h0 | ((unsigned int)h1 << 16);
        rl[c / 2] = (unsigned int)l0 | ((unsigned int)l1 << 16);
    }
}

// ---------------- kargmin: 512 blocks x 256 thr (4 waves) ----------------
// Block = 64 points; wave owns 16 points x ALL 1024 codes (no cross-wave
// merge). Codebook streamed in 32-code chunks through padded LDS (row =
// 136 ushorts => even bank tiling) with a 2-deep reg pipeline: GLD of
// chunk c+2 issued one full chunk before its SWR -> vmcnt wait ~0.
#define KCHUNK 32
#define ROWPAD 136   // ushorts per padded code row (128 + 8)

#define GLD(reg, ch) {                                                        \
        const u32x4* gp = reinterpret_cast<const u32x4*>(ebhl) + (ch) * 512;  \
        reg[0] = gp[tid];                                                     \
        reg[1] = gp[tid + 256];                                               \
    }
#define SWR(bufp, reg) {                                                      \
        _Pragma("unroll")                                                     \
        for (int i = 0; i < 2; ++i) {                                         \
            int gci = tid + i * 256;                                          \
            int code = gci >> 4, cb = gci & 15;                               \
            *reinterpret_cast<u32x4*>(&(bufp)[code * ROWPAD + cb * 8]) = reg[i];\
        }                                                                     \
    }
#define COMPT2(bufp, ch) {                                                    \
        _Pragma("unroll")                                                     \
        for (int t = 0; t < 2; ++t) {                                         \
            const unsigned short* rb = &(bufp)[(t * 16 + lc) * ROWPAD];       \
            short8 eh0 = *reinterpret_cast<const short8*>(rb + rg * 8);       \
            short8 eh1 = *reinterpret_cast<const short8*>(rb + 32 + rg * 8);  \
            short8 el0 = *reinterpret_cast<const short8*>(rb + 64 + rg * 8);  \
            short8 el1 = *reinterpret_cast<const short8*>(rb + 96 + rg * 8);  \
            f32x4 pA = {0.f, 0.f, 0.f, 0.f};                                  \
            f32x4 pB = {0.f, 0.f, 0.f, 0.f};                                  \
            pA = __builtin_amdgcn_mfma_f32_16x16x32_bf16(zh0, eh0, pA, 0, 0, 0);\
            pA = __builtin_amdgcn_mfma_f32_16x16x32_bf16(zh1, eh1, pA, 0, 0, 0);\
            pB = __builtin_amdgcn_mfma_f32_16x16x32_bf16(zh0, el0, pB, 0, 0, 0);\
            pB = __builtin_amdgcn_mfma_f32_16x16x32_bf16(zh1, el1, pB, 0, 0, 0);\
            pB = __builtin_amdgcn_mfma_f32_16x16x32_bf16(zl0, eh0, pB, 0, 0, 0);\
            pB = __builtin_amdgcn_mfma_f32_16x16x32_bf16(zl1, eh1, pB, 0, 0, 0);\
            const int code = (ch) * KCHUNK + t * 16 + lc;                     \
            const float ne_c = sne[code];                                     \
            _Pragma("unroll")                                                 \
            for (int r = 0; r < 4; ++r) {                                     \
                float t1 = nzr[r] + ne_c;                                     \
                float d = fmaf(-2.0f, pA[r] + pB[r], t1);                     \
                float m = fminf(d, b2[r]);                                    \
                bool lt = d < b1[r];                                          \
                b2[r] = lt ? b1[r] : m;                                       \
                k1[r] = lt ? code : k1[r];                                    \
                b1[r] = fminf(d, b1[r]);                                      \
            }                                                                 \
        }                                                                     \
    }

__global__ __launch_bounds__(256) void kargmin_kernel(
    const float* __restrict__ z, const unsigned short* __restrict__ ebhl,
    const float* __restrict__ norms,
    int* __restrict__ idx, unsigned int* __restrict__ counts,
    float* __restrict__ out_idx, float* __restrict__ nzG,
    unsigned int* __restrict__ fixcnt, int* __restrict__ fixlist)
{
    __shared__ float szt[64][68];                   // 17408 B
    __shared__ float snz[64];                       // 256 B
    __shared__ float sne[N_E];                      // 4096 B
    __shared__ unsigned short sbuf[2][KCHUNK * ROWPAD]; // 2 x 8704 B

    const int tid = threadIdx.x;
    const int wave = tid >> 6;
    const int lane = tid & 63;
    const int lc = lane & 15;
    const int rg = lane >> 4;
    const int pbase = blockIdx.x * 64;
    const int b = pbase >> 10;
    const int hw0 = pbase & 1023;

    // stage z tile: 64 consecutive pts per c -> 256B coalesced
    {
        const int pt = tid & 63, c0 = tid >> 6;
#pragma unroll
        for (int cg = 0; cg < 16; ++cg) {
            int c = cg * 4 + c0;
            szt[pt][c] = z[((b * E_DIM + c) << 10) + hw0 + pt];
        }
    }
    *reinterpret_cast<float4*>(&sne[tid * 4]) =
        *reinterpret_cast<const float4*>(norms + tid * 4);
    __syncthreads();
    if (tid < 64) {
        float v = np_sum64_sq(&szt[tid][0]);
        snz[tid] = v;
        nzG[pbase + tid] = v;
    }
    __syncthreads();

    // A-fragments: wave's point pa = wave*16+lc, K-chunks per rg
    const int pa = wave * 16 + lc;
    float4 zv0 = *reinterpret_cast<const float4*>(&szt[pa][rg * 8]);
    float4 zv1 = *reinterpret_cast<const float4*>(&szt[pa][rg * 8 + 4]);
    float4 zv2 = *reinterpret_cast<const float4*>(&szt[pa][32 + rg * 8]);
    float4 zv3 = *reinterpret_cast<const float4*>(&szt[pa][32 + rg * 8 + 4]);
    float zt0[8] = {zv0.x, zv0.y, zv0.z, zv0.w, zv1.x, zv1.y, zv1.z, zv1.w};
    float zt1[8] = {zv2.x, zv2.y, zv2.z, zv2.w, zv3.x, zv3.y, zv3.z, zv3.w};
    short8 zh0, zl0, zh1, zl1;
#pragma unroll
    for (int j = 0; j < 8; ++j) {
        unsigned short h0 = rn_bf16(zt0[j]);
        zh0[j] = (short)h0;
        zl0[j] = (short)rn_bf16(zt0[j] - bf16_to_f(h0));
        unsigned short h1 = rn_bf16(zt1[j]);
        zh1[j] = (short)h1;
        zl1[j] = (short)rn_bf16(zt1[j] - bf16_to_f(h1));
    }

    float nzr[4];
#pragma unroll
    for (int r = 0; r < 4; ++r) nzr[r] = snz[wave * 16 + rg * 4 + r];

    float b1[4] = {3.4028235e38f, 3.4028235e38f, 3.4028235e38f, 3.4028235e38f};
    float b2[4] = {3.4028235e38f, 3.4028235e38f, 3.4028235e38f, 3.4028235e38f};
    int k1[4] = {0, 0, 0, 0};

    u32x4 rA[2], rB[2];
    GLD(rA, 0);
    SWR(sbuf[0], rA);
    GLD(rB, 1);
    __syncthreads();

    for (int it = 0; it < 16; ++it) {
        const int ch0 = 2 * it, ch1 = 2 * it + 1;
        // phase A: compute chunk ch0 from buf0; buf1 <- rB (chunk ch0+1)
        COMPT2(sbuf[0], ch0);
        SWR(sbuf[1], rB);
        if (it < 15) GLD(rA, ch0 + 2);
        __syncthreads();
        // phase B: compute chunk ch1 from buf1; buf0 <- rA (chunk ch1+1)
        COMPT2(sbuf[1], ch1);
        if (it < 15) {
            SWR(sbuf[0], rA);
            GLD(rB, ch1 + 2);
        }
        __syncthreads();
    }

    // intra-wave top-2 merge across the 16 code-column lanes
#pragma unroll
    for (int off = 1; off < 16; off <<= 1) {
#pragma unroll
        for (int r = 0; r < 4; ++r) {
            float ob1 = __shfl_xor(b1[r], off, 64);
            float ob2 = __shfl_xor(b2[r], off, 64);
            int   ok1 = __shfl_xor(k1[r], off, 64);
            float nb2 = fminf(fmaxf(b1[r], ob1), fminf(b2[r], ob2));
            if (ob1 < b1[r] || (ob1 == b1[r] && ok1 < k1[r])) { b1[r] = ob1; k1[r] = ok1; }
            b2[r] = nb2;
        }
    }

    if (lc == 0) {
#pragma unroll
        for (int r = 0; r < 4; ++r) {
            int p = pbase + wave * 16 + rg * 4 + r;
            idx[p] = k1[r];
            out_idx[p] = (float)k1[r];
            atomicAdd(&counts[k1[r]], 1u);
            float gap = b2[r] - b1[r];
            if (gap < 3e-5f || (b1[r] >= 128.f && gap < 6.5e-5f)) {
                unsigned int slot = atomicAdd(fixcnt, 1u);
                if (slot < FIXCAP) fixlist[slot] = p;
            }
        }
    }
}

// ---------------- kfix: wave-per-flagged-point, coalesced fp64 ----------------
__global__ __launch_bounds__(256) void kfix_kernel(
    const float* __restrict__ z, const float* __restrict__ emb,
    const float* __restrict__ norms, const float* __restrict__ nzG,
    int* __restrict__ idx, unsigned int* __restrict__ counts,
    float* __restrict__ out_idx,
    const unsigned int* __restrict__ fixcnt,
    const int* __restrict__ fixlist)
{
    unsigned int n = *fixcnt;
    if (n > FIXCAP) n = FIXCAP;
    const int lane = threadIdx.x & 63;
    const int kk = lane & 15;     // code-in-batch
    const int cg = lane >> 4;     // c-quarter 0..3
    const unsigned int slot = blockIdx.x * 4 + (threadIdx.x >> 6);

    for (unsigned int it = slot; it < n; it += 4096) {
        const int p = fixlist[it];
        const int b = p >> 10, hw = p & 1023;
        // this lane's 16 z components (c = cg*16 + j); same addr across the
        // 16 kk-lanes -> broadcast loads
        double zc[16];
#pragma unroll
        for (int j = 0; j < 16; ++j)
            zc[j] = (double)z[((b * E_DIM + cg * 16 + j) << 10) + hw];
        const float nz = nzG[p];

        float best = 3.4028235e38f;
        int bestk = 0;
        for (int batch = 0; batch < 64; ++batch) {
            const int k = batch * 16 + kk;
            const float4* er = reinterpret_cast<const float4*>(
                emb + (size_t)k * E_DIM + cg * 16);
            double acc = 0.0;
#pragma unroll
            for (int i = 0; i < 4; ++i) {
                float4 ev = er[i];
                acc += (double)ev.x * zc[i * 4 + 0];
                acc += (double)ev.y * zc[i * 4 + 1];
                acc += (double)ev.z * zc[i * 4 + 2];
                acc += (double)ev.w * zc[i * 4 + 3];
            }
            // sum the 4 c-quarters (butterfly over lane bits 4,5)
            acc += __shfl_xor(acc, 16, 64);
            acc += __shfl_xor(acc, 32, 64);
            float dotf = (float)acc;
            float d;
            {
#pragma clang fp contract(off)
                float t1 = nz + norms[k];
                d = t1 - 2.0f * dotf;
            }
            if (d < best) { best = d; bestk = k; }  // ascending k per lane
        }
        // merge the 16 kk-lanes, index-aware (first index on ties)
#pragma unroll
        for (int off = 1; off < 16; off <<= 1) {
            float ob = __shfl_xor(best, off, 64);
            int   ok = __shfl_xor(bestk, off, 64);
            if (ob < best || (ob == best && ok < bestk)) { best = ob; bestk = ok; }
        }
        if (lane == 0) {
            int oldk = idx[p];
            if (bestk != oldk) {
                idx[p] = bestk;
                out_idx[p] = (float)bestk;
                atomicSub(&counts[oldk], 1u);
                atomicAdd(&counts[bestk], 1u);
            }
        }
    }
}

// ---------------- kzq: LDS-transpose gather + fused loss ----------------
// 512 blocks x 256 thr; block = 64 points. Stage the 64 selected emb rows
// coalesced into padded LDS, then emit (B,C,H,W) with fully coalesced
// loads/stores; LDS column reads are 2-way (free).
__global__ __launch_bounds__(256) void kzq_kernel(
    const float* __restrict__ z, const float* __restrict__ emb,
    const int* __restrict__ idx,
    float* __restrict__ zq_out, float* __restrict__ loss_accum)
{
    __shared__ float se[64 * 65];
    __shared__ int sk[64];
    __shared__ float wsum[4];

    const int tid = threadIdx.x;
    const int pbase = blockIdx.x * 64;
    const int b = pbase >> 10;
    const int hw0 = pbase & 1023;

    if (tid < 64) sk[tid] = idx[pbase + tid];
    __syncthreads();

    // stage rows: 1024 float4s, 4 per thread, contiguous within each row
    const float4* emb4 = reinterpret_cast<const float4*>(emb);
#pragma unroll
    for (int i = 0; i < 4; ++i) {
        int fi = tid + i * 256;
        int row = fi >> 4, c4 = fi & 15;
        float4 v = emb4[(size_t)sk[row] * 16 + c4];
        se[row * 65 + c4 * 4 + 0] = v.x;
        se[row * 65 + c4 * 4 + 1] = v.y;
        se[row * 65 + c4 * 4 + 2] = v.z;
        se[row * 65 + c4 * 4 + 3] = v.w;
    }
    __syncthreads();

    // emit: thread (p = tid&63, cgrp = tid>>6) handles 16 c's
    const int p = tid & 63;
    const int cgrp = tid >> 6;
    float ssum = 0.f;
#pragma unroll
    for (int j = 0; j < 16; ++j) {
        const int c = cgrp * 16 + j;
        const int f = ((b * E_DIM + c) << 10) + hw0 + p;
        float q = se[p * 65 + c];
        float zv = z[f];
        __builtin_nontemporal_store(q, &zq_out[f]);
        float dd = q - zv;
        ssum += dd * dd;
    }
#pragma unroll
    for (int off = 32; off > 0; off >>= 1) ssum += __shfl_down(ssum, off, 64);
    const int lane = tid & 63, wid = tid >> 6;
    if (lane == 0) wsum[wid] = ssum;
    __syncthreads();
    if (tid == 0)
        atomicAdd(loss_accum, wsum[0] + wsum[1] + wsum[2] + wsum[3]);
}

// one-hot "ones" scatter (buffer pre-zeroed by hipMemsetAsync node)
__global__ void kones_kernel(const int* __restrict__ idx, float* __restrict__ oh)
{
    int p = blockIdx.x * blockDim.x + threadIdx.x;
    if (p < N_PTS)
        oh[(size_t)p * N_E + idx[p]] = 1.0f;
}

__global__ void kfin_kernel(const unsigned int* __restrict__ counts,
                            const float* __restrict__ loss_accum,
                            float* __restrict__ out_loss, float* __restrict__ out_perp)
{
    int k = threadIdx.x;
    float em = (float)counts[k] / (float)N_PTS;
    float v = em * logf(em + 1e-10f);
#pragma unroll
    for (int off = 32; off > 0; off >>= 1) v += __shfl_down(v, off, 64);
    __shared__ float sb[16];
    int lane = k & 63, wid = k >> 6;
    if (lane == 0) sb[wid] = v;
    __syncthreads();
    if (k == 0) {
        float ssum = 0.f;
#pragma unroll
        for (int i = 0; i < 16; ++i) ssum += sb[i];
        *out_perp = expf(-ssum);
        *out_loss = 1.25f * (*loss_accum) / 2097152.f;
    }
}

extern "C" void kernel_launch(void* const* d_in, const int* in_sizes, int n_in,
                              void* d_out, int out_size, void* d_ws, size_t ws_size,
                              hipStream_t stream) {
    const float* z   = (const float*)d_in[0];
    const float* emb = (const float*)d_in[1];
    float* out = (float*)d_out;

    float* out_loss = out;
    float* out_zq   = out + OFF_ZQ;
    float* out_perp = out + OFF_PERP;
    float* out_oh   = out + OFF_OH;
    float* out_idx  = out + OFF_IDX;

    char* ws = (char*)d_ws;
    float*          loss_accum = (float*)(ws + WS_LOSS);
    unsigned int*   ws_head    = (unsigned int*)(ws + WS_LOSS);
    unsigned int*   fixcnt     = (unsigned int*)(ws + WS_FIXCNT);
    unsigned int*   counts     = (unsigned int*)(ws + WS_COUNTS);
    float*          norms      = (float*)(ws + WS_NORMS);
    int*            idx        = (int*)(ws + WS_IDX);
    int*            fixlist    = (int*)(ws + WS_FIXLIST);
    float*          nzG        = (float*)(ws + WS_NZ);
    unsigned short* ebhl       = (unsigned short*)(ws + WS_EBHL);

    // one-hot zero-fill at fill-primitive speed (~6.4 TB/s measured)
    hipMemsetAsync(out_oh, 0, (size_t)N_PTS * N_E * sizeof(float), stream);

    eprep_kernel<<<(N_E + 255) / 256, 256, 0, stream>>>(emb, ebhl, norms,
                                                        ws_head, counts);
    kargmin_kernel<<<N_PTS / 64, 256, 0, stream>>>(z, ebhl, norms, idx, counts,
                                                   out_idx, nzG, fixcnt, fixlist);
    kfix_kernel<<<1024, 256, 0, stream>>>(z, emb, norms, nzG, idx, counts,
                                          out_idx, fixcnt, fixlist);
    kzq_kernel<<<N_PTS / 64, 256, 0, stream>>>(z, emb, idx, out_zq, loss_accum);
    kones_kernel<<<N_PTS / 256, 256, 0, stream>>>(idx, out_oh);
    kfin_kernel<<<1, 1024, 0, stream>>>(counts, loss_accum, out_loss, out_perp);
}